// Round 1
// 2041.200 us; speedup vs baseline: 2.3371x; 2.3371x over previous
//
#include <hip/hip_runtime.h>
#include <hip/hip_fp16.h>

typedef unsigned short u16;
typedef _Float16 half8 __attribute__((ext_vector_type(8)));
typedef _Float16 half4 __attribute__((ext_vector_type(4)));
typedef float floatx4 __attribute__((ext_vector_type(4)));

#define NB 32
#define NS 256
#define NSE 1024
#define ND 512
#define NV 8000
#define NL 4
#define NH 8
#define NDK 64
#define BN_EPS 1e-3f

// ---- async global->LDS, 16B per lane (dest = wave-uniform base + lane*16) ----
typedef const __attribute__((address_space(1))) void* gas_ptr;
typedef __attribute__((address_space(3))) void* las_ptr;
__device__ __forceinline__ void gload16(const void* g, void* l) {
    __builtin_amdgcn_global_load_lds((gas_ptr)g, (las_ptr)l, 16, 0, 0);
}

// ---------------- fp32 -> fp16 cast (8 elems/thread) ----------------
__global__ __launch_bounds__(256) void k_cast(const float* __restrict__ in, _Float16* __restrict__ out) {
    size_t i = ((size_t)blockIdx.x * 256 + threadIdx.x) * 8;
    float4 a = *(const float4*)(in + i);
    float4 b = *(const float4*)(in + i + 4);
    half8 o;
    o[0] = (_Float16)a.x; o[1] = (_Float16)a.y; o[2] = (_Float16)a.z; o[3] = (_Float16)a.w;
    o[4] = (_Float16)b.x; o[5] = (_Float16)b.y; o[6] = (_Float16)b.z; o[7] = (_Float16)b.w;
    *(half8*)(out + i) = o;
}

// ---------------- embedding + positional (fp32 in, fp16 out) ----------------
__global__ __launch_bounds__(256) void k_embed(const int* __restrict__ seq,
                                               const float* __restrict__ emb,
                                               const float* __restrict__ pos,
                                               _Float16* __restrict__ x) {
    size_t i = ((size_t)blockIdx.x * 256 + threadIdx.x) * 8;
    int tok = (int)(i / ND);
    int d = (int)(i % ND);
    int s = tok % NS;
    int t = seq[tok];
    const float* ep = emb + (size_t)t * ND + d;
    const float* pp = pos + (size_t)s * ND + d;
    half8 o;
    for (int j = 0; j < 8; j++) o[j] = (_Float16)(ep[j] + pp[j]);
    *(half8*)(x + i) = o;
}

// ---------------- residual + BatchNorm (inference); params fp32 ----------------
__global__ __launch_bounds__(256) void k_bnres(const _Float16* __restrict__ xin, const _Float16* __restrict__ a,
                                               const float* __restrict__ gamma, const float* __restrict__ beta,
                                               const float* __restrict__ mean, const float* __restrict__ var,
                                               _Float16* __restrict__ xout) {
    size_t i = ((size_t)blockIdx.x * 256 + threadIdx.x) * 8;
    int d = (int)(i % ND);
    half8 xv = *(const half8*)(xin + i);
    half8 av = *(const half8*)(a + i);
    half8 o;
    for (int j = 0; j < 8; j++) {
        float v = (float)xv[j] + (float)av[j];
        float r = rsqrtf(var[d + j] + BN_EPS);
        o[j] = (_Float16)(((v - mean[d + j]) * r) * gamma[d + j] + beta[d + j]);
    }
    *(half8*)(xout + i) = o;
}

// ------------- weight transpose + cast: in fp32 [R][C] -> out fp16 [C][R] -------------
__global__ void k_transpose_w(const float* __restrict__ in, _Float16* __restrict__ out, int R, int C) {
    __shared__ float tile[32][33];
    int b = blockIdx.z;
    int c0 = blockIdx.x * 32, r0 = blockIdx.y * 32;
    const float* pin = in + (size_t)b * R * C;
    _Float16* pout = out + (size_t)b * R * C;
    int tx = threadIdx.x, ty = threadIdx.y;                  // block (32,8)
    for (int j = 0; j < 32; j += 8)
        tile[ty + j][tx] = pin[(size_t)(r0 + ty + j) * C + c0 + tx];
    __syncthreads();
    for (int j = 0; j < 32; j += 8)
        pout[(size_t)(c0 + ty + j) * R + r0 + tx] = (_Float16)tile[tx][ty + j];
}

// ---------------- fp16 MFMA GEMM: C[M,N] = A[M,K] @ Bt[N,K]^T + bias ----------
// BM x 128 tile, 256 thr = 4 waves (2x2). m97 recipe: global_load_lds width-16
// into linear (unpadded) LDS, 2 barriers/K-step. Epilogue goes through a
// per-wave LDS transpose so all global stores are wide & contiguous.
// outmode: 0 = fp16 row-major, 1 = fp16 per-batch transposed [b][col][s],
//          2 = fp32 row-major. Bt must have >= ceil(N/128)*128 rows allocated.
template<int BM>
__global__ __launch_bounds__(256) void k_gemm(const _Float16* __restrict__ A, const _Float16* __restrict__ Bt,
                                              const float* __restrict__ bias, void* __restrict__ Cout,
                                              int M, int N, int K, int relu, int outmode, int Sb) {
    constexpr int BN = 128;
    constexpr int BK = 64;
    constexpr int MI = BM / 32;                 // A-frags per wave (rows/16)
    __shared__ __align__(16) _Float16 smem[BM * BK + BN * BK];
    _Float16* As = smem;                        // [BM][64] linear
    _Float16* Bs = smem + BM * BK;              // [128][64] linear

    int tid = threadIdx.x;
    int wid = tid >> 6, lane = tid & 63, quad = lane >> 4, r = lane & 15;

    // bijective XCD-aware swizzle: XCD x gets a contiguous chunk of tiles
    int nwg = gridDim.x * gridDim.y;
    int orig = blockIdx.y * gridDim.x + blockIdx.x;
    int q8 = nwg >> 3, r8 = nwg & 7;
    int xcd = orig & 7, loc = orig >> 3;
    int swz = (xcd < r8 ? xcd * (q8 + 1) : r8 * (q8 + 1) + (xcd - r8) * q8) + loc;
    int m0 = (swz / gridDim.x) * BM;
    int n0 = (swz % gridDim.x) * BN;

    int wm = (wid >> 1) * (BM / 2);             // wave tile: (BM/2) x 64
    int wn = (wid & 1) * 64;

    floatx4 zf = {0.f, 0.f, 0.f, 0.f};
    floatx4 acc[MI][4];
    for (int i = 0; i < MI; i++) for (int j = 0; j < 4; j++) acc[i][j] = zf;

    // staging: each wave-issue covers 8 rows (8 lanes/row * 16 B = 128 B = one row of 64 halfs)
    int srow = wid * 8 + (lane >> 3);
    int scol = (lane & 7) * 8;

    for (int k0 = 0; k0 < K; k0 += BK) {
        __syncthreads();
        {
            const _Float16* abase = A + (size_t)(m0 + srow) * K + k0 + scol;
            for (int i = 0; i < BM / 32; i++)
                gload16(abase + (size_t)i * 32 * K, As + (i * 32 + wid * 8) * BK);
            const _Float16* bbase = Bt + (size_t)(n0 + srow) * K + k0 + scol;
            for (int i = 0; i < 4; i++)
                gload16(bbase + (size_t)i * 32 * K, Bs + (i * 32 + wid * 8) * BK);
        }
        __syncthreads();   // compiler drains vmcnt(0) here -> LDS tiles ready
        for (int ks = 0; ks < BK; ks += 32) {
            half8 af[MI], bg[4];
#pragma unroll
            for (int i = 0; i < MI; i++) af[i] = *(const half8*)&As[(wm + i * 16 + r) * BK + ks + quad * 8];
#pragma unroll
            for (int j = 0; j < 4; j++)  bg[j] = *(const half8*)&Bs[(wn + j * 16 + r) * BK + ks + quad * 8];
#pragma unroll
            for (int i = 0; i < MI; i++)
#pragma unroll
                for (int j = 0; j < 4; j++)
                    acc[i][j] = __builtin_amdgcn_mfma_f32_16x16x32_f16(af[i], bg[j], acc[i][j], 0, 0, 0);
        }
    }

    __syncthreads();   // all ds_reads done; smem reusable by epilogue

    if (outmode == 1) {
        // C/D frag: row = quad*4+g (4 consecutive output s), col = lane&15.
        // Pack the 4 consecutive-s values into one 8-B half4 store along s.
        for (int i = 0; i < MI; i++) {
            int grow = m0 + wm + i * 16 + quad * 4;
            int b = grow / Sb, s = grow - b * Sb;
            _Float16* outp = (_Float16*)Cout + (size_t)b * N * Sb + s;
#pragma unroll
            for (int j = 0; j < 4; j++) {
                int col = n0 + wn + j * 16 + r;
                float bv = bias[col];
                half4 h;
#pragma unroll
                for (int g = 0; g < 4; g++) {
                    float v = acc[i][j][g] + bv;
                    if (relu) v = fmaxf(v, 0.0f);
                    h[g] = (_Float16)v;
                }
                *(half4*)(outp + (size_t)col * Sb) = h;
            }
        }
    } else {
        // per-wave fp32 staging tile [16][68] (disjoint per wave -> no barrier)
        float* Ep = (float*)(void*)smem + wid * (16 * 68);
        int rr = lane >> 4;            // 0..3
        int c = (lane & 15) * 4;       // 0..60
        for (int i = 0; i < MI; i++) {
#pragma unroll
            for (int j = 0; j < 4; j++) {
                int col = n0 + wn + j * 16 + r;
                float bv = (col < N) ? bias[col] : 0.0f;
#pragma unroll
                for (int g = 0; g < 4; g++) {
                    float v = acc[i][j][g] + bv;
                    if (relu) v = fmaxf(v, 0.0f);
                    Ep[(quad * 4 + g) * 68 + j * 16 + r] = v;
                }
            }
            if (outmode == 0) {
#pragma unroll
                for (int p = 0; p < 4; p++) {
                    float4 v = *(float4*)&Ep[(p * 4 + rr) * 68 + c];
                    half4 h;
                    h[0] = (_Float16)v.x; h[1] = (_Float16)v.y; h[2] = (_Float16)v.z; h[3] = (_Float16)v.w;
                    int grow = m0 + wm + i * 16 + p * 4 + rr;
                    *(half4*)&((_Float16*)Cout)[(size_t)grow * N + n0 + wn + c] = h;   // 8 B/lane, 128 B contiguous per row
                }
            } else {
#pragma unroll
                for (int p = 0; p < 4; p++) {
                    int gcol = n0 + wn + c;
                    if (gcol < N) {
                        float4 v = *(float4*)&Ep[(p * 4 + rr) * 68 + c];
                        int grow = m0 + wm + i * 16 + p * 4 + rr;
                        *(float4*)&((float*)Cout)[(size_t)grow * N + gcol] = v;        // 16 B/lane, 256 B contiguous
                    }
                }
            }
        }
    }
}

// ---------------- fused flash attention (fp16 in/out, fp32 softmax) ----------------
__global__ __launch_bounds__(256) void k_attn(const _Float16* __restrict__ Q, const _Float16* __restrict__ Kb,
                                              const _Float16* __restrict__ Vt, _Float16* __restrict__ O,
                                              int Sk, int causal) {
    __shared__ _Float16 Plds[4][16][72];
    int qt = blockIdx.x, h = blockIdx.y, b = blockIdx.z;
    int tid = threadIdx.x;
    int w = tid >> 6, lane = tid & 63, quad = lane >> 4, r = lane & 15;
    int qbase = qt * 64 + w * 16;

    floatx4 zf = {0.f, 0.f, 0.f, 0.f};
    half8 aq[2];
    const _Float16* qptr = Q + (size_t)(b * NS + qbase + r) * ND + h * NDK;
    aq[0] = *(const half8*)(qptr + quad * 8);
    aq[1] = *(const half8*)(qptr + 32 + quad * 8);

    floatx4 Of[4];
    for (int j = 0; j < 4; j++) Of[j] = zf;
    float mrow[4], lrow[4];
    for (int g = 0; g < 4; g++) { mrow[g] = -1e30f; lrow[g] = 0.0f; }

    int ntiles = causal ? (qt + 1) : (Sk >> 6);

    for (int kt = 0; kt < ntiles; kt++) {
        floatx4 sc[4];
        for (int j = 0; j < 4; j++) sc[j] = zf;
        for (int t = 0; t < 2; t++) {
            for (int j = 0; j < 4; j++) {
                const _Float16* kptr = Kb + (size_t)(b * Sk + kt * 64 + j * 16 + r) * ND + h * NDK + t * 32 + quad * 8;
                half8 bk = *(const half8*)kptr;
                sc[j] = __builtin_amdgcn_mfma_f32_16x16x32_f16(aq[t], bk, sc[j], 0, 0, 0);
            }
        }
        float s[4][4], tmax[4];
        for (int g = 0; g < 4; g++) tmax[g] = -1e30f;
        for (int j = 0; j < 4; j++) {
            int key = kt * 64 + j * 16 + r;
            for (int g = 0; g < 4; g++) {
                float v = sc[j][g] * 0.125f;
                int qi = qbase + quad * 4 + g;
                if (causal && key >= qi) v = -1e30f;
                s[j][g] = v;
                tmax[g] = fmaxf(tmax[g], v);
            }
        }
        for (int off = 1; off < 16; off <<= 1)
            for (int g = 0; g < 4; g++)
                tmax[g] = fmaxf(tmax[g], __shfl_xor(tmax[g], off, 64));
        float alpha[4], psum[4];
        for (int g = 0; g < 4; g++) {
            float mnew = fmaxf(mrow[g], tmax[g]);
            alpha[g] = (mnew <= -1e29f) ? 1.0f : __expf(mrow[g] - mnew);
            mrow[g] = mnew;
            psum[g] = 0.0f;
        }
        for (int j = 0; j < 4; j++) {
            for (int g = 0; g < 4; g++) {
                float p = (s[j][g] <= -1e29f) ? 0.0f : __expf(s[j][g] - mrow[g]);
                psum[g] += p;
                Plds[w][quad * 4 + g][j * 16 + r] = (_Float16)p;
            }
        }
        for (int off = 1; off < 16; off <<= 1)
            for (int g = 0; g < 4; g++)
                psum[g] += __shfl_xor(psum[g], off, 64);
        for (int g = 0; g < 4; g++) lrow[g] = lrow[g] * alpha[g] + psum[g];
        for (int j = 0; j < 4; j++)
            for (int g = 0; g < 4; g++)
                Of[j][g] *= alpha[g];
        __syncthreads();
        for (int t = 0; t < 2; t++) {
            half8 ap = *(const half8*)&Plds[w][r][t * 32 + quad * 8];
            for (int j = 0; j < 4; j++) {
                const _Float16* vptr = Vt + (size_t)((b * NH + h) * NDK + j * 16 + r) * Sk + kt * 64 + t * 32 + quad * 8;
                half8 bv = *(const half8*)vptr;
                Of[j] = __builtin_amdgcn_mfma_f32_16x16x32_f16(ap, bv, Of[j], 0, 0, 0);
            }
        }
        __syncthreads();
    }
    for (int j = 0; j < 4; j++) {
        for (int g = 0; g < 4; g++) {
            int row = qbase + quad * 4 + g;
            float inv = (lrow[g] > 0.f) ? 1.0f / lrow[g] : 0.0f;
            O[(size_t)(b * NS + row) * ND + h * NDK + j * 16 + r] = (_Float16)(Of[j][g] * inv);
        }
    }
}

extern "C" void kernel_launch(void* const* d_in, const int* in_sizes, int n_in,
                              void* d_out, int out_size, void* d_ws, size_t ws_size,
                              hipStream_t stream) {
    const int*   seq  = (const int*)d_in[0];
    const float* enc  = (const float*)d_in[1];
    const float* pos  = (const float*)d_in[2];
    const float* emb  = (const float*)d_in[3];
    const float* Wout = (const float*)d_in[4];
    const float* bout = (const float*)d_in[5];
    const float* W1   = (const float*)d_in[6];
    const float* b1   = (const float*)d_in[7];
    const float* W2   = (const float*)d_in[8];
    const float* b2   = (const float*)d_in[9];
    const float* Wq_bot = (const float*)d_in[10];
    const float* Wk_bot = (const float*)d_in[11];
    const float* Wv_bot = (const float*)d_in[12];
    const float* Wo_bot = (const float*)d_in[13];
    const float* bq_bot = (const float*)d_in[14];
    const float* bk_bot = (const float*)d_in[15];
    const float* bv_bot = (const float*)d_in[16];
    const float* bo_bot = (const float*)d_in[17];
    const float* Wq_mid = (const float*)d_in[18];
    const float* Wk_mid = (const float*)d_in[19];
    const float* Wv_mid = (const float*)d_in[20];
    const float* Wo_mid = (const float*)d_in[21];
    const float* bq_mid = (const float*)d_in[22];
    const float* bk_mid = (const float*)d_in[23];
    const float* bv_mid = (const float*)d_in[24];
    const float* bo_mid = (const float*)d_in[25];
    const float* gam[3] = {(const float*)d_in[26], (const float*)d_in[30], (const float*)d_in[34]};
    const float* bet[3] = {(const float*)d_in[27], (const float*)d_in[31], (const float*)d_in[35]};
    const float* mea[3] = {(const float*)d_in[28], (const float*)d_in[32], (const float*)d_in[36]};
    const float* vr [3] = {(const float*)d_in[29], (const float*)d_in[33], (const float*)d_in[37]};

    char* wp = (char*)d_ws;
    auto alloc = [&](size_t elems) -> _Float16* {
        _Float16* p = (_Float16*)wp;
        wp += ((elems * 2 + 255) / 256) * 256;
        return p;
    };
    const size_t DD = (size_t)ND * ND;
    const int NVP = 8064;                       // NV padded to multiple of 128 for guard-free staging
    _Float16* WqTb = alloc(NL * DD);
    _Float16* WkTb = alloc(NL * DD);
    _Float16* WvTb = alloc(NL * DD);
    _Float16* WoTb = alloc(NL * DD);
    _Float16* WqTm = alloc(NL * DD);
    _Float16* WkTm = alloc(NL * DD);
    _Float16* WvTm = alloc(NL * DD);
    _Float16* WoTm = alloc(NL * DD);
    _Float16* W1T  = alloc(NL * DD);
    _Float16* W2T  = alloc(NL * DD);
    _Float16* WoutT = alloc((size_t)NVP * ND);
    const size_t XSZ = (size_t)NB * NS * ND;    // 4.19M elems
    _Float16* x   = alloc(XSZ);
    _Float16* qb  = alloc(XSZ);
    _Float16* kb  = alloc(XSZ);
    _Float16* vts = alloc(XSZ);                 // V^T self  [B,D,S]
    _Float16* ao  = alloc(XSZ);
    const size_t ESZ = (size_t)NB * NSE * ND;   // 16.78M elems
    _Float16* ench  = alloc(ESZ);               // fp16 encoder
    _Float16* kenc  = alloc(ESZ);
    _Float16* vtenc = alloc(ESZ);               // V^T cross [B,D,SE]

    // zero WoutT's padded tail rows (NaN-safe staging for the vocab GEMM)
    hipMemsetAsync(WoutT + (size_t)NV * ND, 0, (size_t)(NVP - NV) * ND * sizeof(_Float16), stream);

    dim3 tb(32, 8);
    k_transpose_w<<<dim3(ND / 32, ND / 32, NL), tb, 0, stream>>>(Wq_bot, WqTb, ND, ND);
    k_transpose_w<<<dim3(ND / 32, ND / 32, NL), tb, 0, stream>>>(Wk_bot, WkTb, ND, ND);
    k_transpose_w<<<dim3(ND / 32, ND / 32, NL), tb, 0, stream>>>(Wv_bot, WvTb, ND, ND);
    k_transpose_w<<<dim3(ND / 32, ND / 32, NL), tb, 0, stream>>>(Wo_bot, WoTb, ND, ND);
    k_transpose_w<<<dim3(ND / 32, ND / 32, NL), tb, 0, stream>>>(Wq_mid, WqTm, ND, ND);
    k_transpose_w<<<dim3(ND / 32, ND / 32, NL), tb, 0, stream>>>(Wk_mid, WkTm, ND, ND);
    k_transpose_w<<<dim3(ND / 32, ND / 32, NL), tb, 0, stream>>>(Wv_mid, WvTm, ND, ND);
    k_transpose_w<<<dim3(ND / 32, ND / 32, NL), tb, 0, stream>>>(Wo_mid, WoTm, ND, ND);
    k_transpose_w<<<dim3(ND / 32, ND / 32, NL), tb, 0, stream>>>(W1, W1T, ND, ND);
    k_transpose_w<<<dim3(ND / 32, ND / 32, NL), tb, 0, stream>>>(W2, W2T, ND, ND);
    k_transpose_w<<<dim3(NV / 32, ND / 32, 1), tb, 0, stream>>>(Wout, WoutT, ND, NV);
    k_cast<<<dim3((int)(ESZ / 8 / 256)), 256, 0, stream>>>(enc, ench);

    auto gemm = [&](const _Float16* A, const _Float16* Bt, const float* bias, void* C,
                    int M, int N, int relu, int outmode, int Sb, int bm) {
        if (bm == 64)
            k_gemm<64><<<dim3((N + 127) / 128, M / 64), 256, 0, stream>>>(A, Bt, bias, C, M, N, ND, relu, outmode, Sb);
        else
            k_gemm<128><<<dim3((N + 127) / 128, M / 128), 256, 0, stream>>>(A, Bt, bias, C, M, N, ND, relu, outmode, Sb);
    };

    k_embed<<<dim3((int)(XSZ / 8 / 256)), 256, 0, stream>>>(seq, emb, pos, x);

    const int M = NB * NS;        // 8192
    const int ME = NB * NSE;      // 32768
    for (int l = 0; l < NL; l++) {
        size_t wofs = (size_t)l * DD;
        size_t bofs = (size_t)l * ND;
        // --- causal self-attention ---
        gemm(x, WqTb + wofs, bq_bot + bofs, qb, M, ND, 0, 0, 0, 64);
        gemm(x, WkTb + wofs, bk_bot + bofs, kb, M, ND, 0, 0, 0, 64);
        gemm(x, WvTb + wofs, bv_bot + bofs, vts, M, ND, 0, 1, NS, 64);
        k_attn<<<dim3(NS / 64, NH, NB), 256, 0, stream>>>(qb, kb, vts, ao, NS, 1);
        gemm(ao, WoTb + wofs, bo_bot + bofs, kb, M, ND, 0, 0, 0, 64);
        k_bnres<<<dim3((int)(XSZ / 8 / 256)), 256, 0, stream>>>(x, kb, gam[0] + bofs, bet[0] + bofs, mea[0] + bofs, vr[0] + bofs, x);
        // --- cross-attention ---
        gemm(x, WqTm + wofs, bq_mid + bofs, qb, M, ND, 0, 0, 0, 64);
        gemm(ench, WkTm + wofs, bk_mid + bofs, kenc, ME, ND, 0, 0, 0, 128);
        gemm(ench, WvTm + wofs, bv_mid + bofs, vtenc, ME, ND, 0, 1, NSE, 128);
        k_attn<<<dim3(NS / 64, NH, NB), 256, 0, stream>>>(qb, kenc, vtenc, ao, NSE, 0);
        gemm(ao, WoTm + wofs, bo_mid + bofs, kb, M, ND, 0, 0, 0, 64);
        k_bnres<<<dim3((int)(XSZ / 8 / 256)), 256, 0, stream>>>(x, kb, gam[1] + bofs, bet[1] + bofs, mea[1] + bofs, vr[1] + bofs, x);
        // --- FFN ---
        gemm(x, W1T + wofs, b1 + bofs, qb, M, ND, 1, 0, 0, 64);
        gemm(qb, W2T + wofs, b2 + bofs, kb, M, ND, 0, 0, 0, 64);
        k_bnres<<<dim3((int)(XSZ / 8 / 256)), 256, 0, stream>>>(x, kb, gam[2] + bofs, bet[2] + bofs, mea[2] + bofs, vr[2] + bofs, x);
    }
    // --- final vocab projection, fp32 straight to d_out ---
    gemm(x, WoutT, bout, (float*)d_out, M, NV, 0, 2, 0, 128);
}

// Round 3
// 1971.945 us; speedup vs baseline: 2.4192x; 1.0351x over previous
//
#include <hip/hip_runtime.h>
#include <hip/hip_fp16.h>

typedef _Float16 half8 __attribute__((ext_vector_type(8)));
typedef _Float16 half4 __attribute__((ext_vector_type(4)));
typedef float floatx4 __attribute__((ext_vector_type(4)));

#define NB 32
#define NS 256
#define NSE 1024
#define ND 512
#define NV 8000
#define NVP 8064
#define NL 4
#define NH 8
#define NDK 64
#define BN_EPS 1e-3f

// ---- async global->LDS, 16B per lane (dest = wave-uniform base + lane*16) ----
typedef const __attribute__((address_space(1))) void* gas_ptr;
typedef __attribute__((address_space(3))) void* las_ptr;
__device__ __forceinline__ void gload16(const void* g, void* l) {
    __builtin_amdgcn_global_load_lds((gas_ptr)g, (las_ptr)l, 16, 0, 0);
}

// ---------------- fp32 -> fp16 cast (8 elems/thread) ----------------
__global__ __launch_bounds__(256) void k_cast(const float* __restrict__ in, _Float16* __restrict__ out) {
    size_t i = ((size_t)blockIdx.x * 256 + threadIdx.x) * 8;
    float4 a = *(const float4*)(in + i);
    float4 b = *(const float4*)(in + i + 4);
    half8 o;
    o[0] = (_Float16)a.x; o[1] = (_Float16)a.y; o[2] = (_Float16)a.z; o[3] = (_Float16)a.w;
    o[4] = (_Float16)b.x; o[5] = (_Float16)b.y; o[6] = (_Float16)b.z; o[7] = (_Float16)b.w;
    *(half8*)(out + i) = o;
}

// ---------------- embedding + positional (fp32 in, fp16 out) ----------------
__global__ __launch_bounds__(256) void k_embed(const int* __restrict__ seq,
                                               const float* __restrict__ emb,
                                               const float* __restrict__ pos,
                                               _Float16* __restrict__ x) {
    size_t i = ((size_t)blockIdx.x * 256 + threadIdx.x) * 8;
    int tok = (int)(i / ND);
    int d = (int)(i % ND);
    int s = tok % NS;
    int t = seq[tok];
    const float* ep = emb + (size_t)t * ND + d;
    const float* pp = pos + (size_t)s * ND + d;
    half8 o;
    for (int j = 0; j < 8; j++) o[j] = (_Float16)(ep[j] + pp[j]);
    *(half8*)(x + i) = o;
}

// ------------- weight transpose + cast: in fp32 [R][C] -> out fp16 [C][R] -------------
// z-batch with independent in/out strides so fused (concatenated) weight layouts can be built.
__global__ void k_transpose_w(const float* __restrict__ in, _Float16* __restrict__ out, int R, int C,
                              long long ostride) {
    __shared__ float tile[32][33];
    int b = blockIdx.z;
    int c0 = blockIdx.x * 32, r0 = blockIdx.y * 32;
    const float* pin = in + (size_t)b * R * C;
    _Float16* pout = out + (size_t)b * ostride;
    int tx = threadIdx.x, ty = threadIdx.y;                  // block (32,8)
    for (int j = 0; j < 32; j += 8)
        tile[ty + j][tx] = pin[(size_t)(r0 + ty + j) * C + c0 + tx];
    __syncthreads();
    for (int j = 0; j < 32; j += 8)
        pout[(size_t)(c0 + ty + j) * R + r0 + tx] = (_Float16)tile[tx][ty + j];
}

// ---------------- fp16 MFMA GEMM: C[M,N] = A[M,K] @ Bt[N,K]^T + bias ----------
// BM x 128 tile, 256 thr = 4 waves (2x2). m97 recipe: global_load_lds width-16
// into linear LDS, 2 barriers/K-step. Epilogue via per-wave LDS transpose for
// wide contiguous stores.
// mode: 0 = fp16 row-major (width 512) into C0
//       1 = fp16 per-batch transposed [b][col][Sb] into C0
//       2 = fp32 row-major width N (vocab, guard col<N) into C0
//       3 = fp16 row-major width 512, out = BN(xres + gemm) into C0
//       4 = fused QKV: seg(n0/512) 0->C0(mode0), 1->C1(mode0), 2->C2(mode1,Sb)
//       5 = fused KV : seg 0->C0(mode0), 1->C1(mode1,Sb)
template<int BM, int BK>
__global__ __launch_bounds__(256) void k_gemm(
    const _Float16* __restrict__ A, const _Float16* __restrict__ Bt,
    const float* __restrict__ bias0, const float* __restrict__ bias1, const float* __restrict__ bias2,
    void* __restrict__ C0, void* __restrict__ C1, void* __restrict__ C2,
    int M, int N, int K, int relu, int mode, int Sb,
    const _Float16* __restrict__ xres,
    const float* __restrict__ bng, const float* __restrict__ bnb,
    const float* __restrict__ bnm, const float* __restrict__ bnv) {
    constexpr int BN = 128;
    constexpr int MI = BM / 32;                 // A-frags per wave
    constexpr int TPR = BK / 8;                 // threads per staged row
    constexpr int RPW = 64 / TPR;               // rows per wave-issue
    constexpr int RPI = 4 * RPW;                // rows per block-issue
    __shared__ __align__(16) _Float16 smem[(BM + BN) * BK];
    _Float16* As = smem;                        // [BM][BK] linear
    _Float16* Bs = smem + BM * BK;              // [BN][BK] linear

    int tid = threadIdx.x;
    int wid = tid >> 6, lane = tid & 63, quad = lane >> 4, r = lane & 15;

    // bijective XCD-aware swizzle
    int nwg = gridDim.x * gridDim.y;
    int orig = blockIdx.y * gridDim.x + blockIdx.x;
    int q8 = nwg >> 3, r8 = nwg & 7;
    int xcd = orig & 7, loc = orig >> 3;
    int swz = (xcd < r8 ? xcd * (q8 + 1) : r8 * (q8 + 1) + (xcd - r8) * q8) + loc;
    int m0 = (swz / gridDim.x) * BM;
    int n0 = (swz % gridDim.x) * BN;

    int wm = (wid >> 1) * (BM / 2);             // wave tile rows
    int wn = (wid & 1) * 64;

    floatx4 zf = {0.f, 0.f, 0.f, 0.f};
    floatx4 acc[MI][4];
    for (int i = 0; i < MI; i++) for (int j = 0; j < 4; j++) acc[i][j] = zf;

    int srow = wid * RPW + lane / TPR;
    int scol = (lane % TPR) * 8;

    for (int k0 = 0; k0 < K; k0 += BK) {
        __syncthreads();
        {
            const _Float16* abase = A + (size_t)(m0 + srow) * K + k0 + scol;
            _Float16* asl = As + (size_t)(wid * RPW) * BK;
#pragma unroll
            for (int i = 0; i < BM / RPI; i++)
                gload16(abase + (size_t)(i * RPI) * K, asl + (size_t)(i * RPI) * BK);
            const _Float16* bbase = Bt + (size_t)(n0 + srow) * K + k0 + scol;
            _Float16* bsl = Bs + (size_t)(wid * RPW) * BK;
#pragma unroll
            for (int i = 0; i < BN / RPI; i++)
                gload16(bbase + (size_t)(i * RPI) * K, bsl + (size_t)(i * RPI) * BK);
        }
        __syncthreads();   // vmcnt(0) drain -> LDS tiles ready
#pragma unroll
        for (int ks = 0; ks < BK; ks += 32) {
            half8 af[MI], bg[4];
#pragma unroll
            for (int i = 0; i < MI; i++) af[i] = *(const half8*)&As[(wm + i * 16 + r) * BK + ks + quad * 8];
#pragma unroll
            for (int j = 0; j < 4; j++)  bg[j] = *(const half8*)&Bs[(wn + j * 16 + r) * BK + ks + quad * 8];
#pragma unroll
            for (int i = 0; i < MI; i++)
#pragma unroll
                for (int j = 0; j < 4; j++)
                    acc[i][j] = __builtin_amdgcn_mfma_f32_16x16x32_f16(af[i], bg[j], acc[i][j], 0, 0, 0);
        }
    }

    __syncthreads();   // K-loop ds_reads done; smem reusable by epilogue

    // ---- resolve output routing (per-block uniform: BN=128 divides 512) ----
    int seg = 0, nloc = n0, om = mode;
    const float* bias = bias0;
    char* C = (char*)C0;
    if (mode == 4) {
        seg = n0 >> 9; nloc = n0 & 511;
        om = (seg == 2) ? 1 : 0;
        C = (char*)(seg == 0 ? C0 : (seg == 1 ? C1 : C2));
        bias = (seg == 0) ? bias0 : ((seg == 1) ? bias1 : bias2);
    } else if (mode == 5) {
        seg = n0 >> 9; nloc = n0 & 511;
        om = seg ? 1 : 0;
        C = (char*)(seg ? C1 : C0);
        bias = seg ? bias1 : bias0;
    }

    if (om == 1) {
        // transposed store: pack 4 consecutive-s accumulator elems into one half4
        for (int i = 0; i < MI; i++) {
            int grow = m0 + wm + i * 16 + quad * 4;
            int b = grow / Sb, s = grow - b * Sb;
            _Float16* outp = (_Float16*)C + (size_t)b * 512 * Sb + s;
#pragma unroll
            for (int j = 0; j < 4; j++) {
                int cb = nloc + wn + j * 16 + r;
                float bv = bias[cb];
                half4 h;
#pragma unroll
                for (int g = 0; g < 4; g++) h[g] = (_Float16)(acc[i][j][g] + bv);
                *(half4*)(outp + (size_t)cb * Sb) = h;
            }
        }
    } else {
        // per-wave fp32 staging tile [16][68] (disjoint per wave -> no barrier)
        float* Ep = (float*)(void*)smem + wid * (16 * 68);
        int rr = lane >> 4;
        int c = (lane & 15) * 4;
        for (int i = 0; i < MI; i++) {
#pragma unroll
            for (int j = 0; j < 4; j++) {
                int cb = nloc + wn + j * 16 + r;
                float bv = (om == 2) ? (cb < N ? bias[cb] : 0.0f) : bias[cb];
#pragma unroll
                for (int g = 0; g < 4; g++) {
                    float v = acc[i][j][g] + bv;
                    if (relu) v = fmaxf(v, 0.0f);
                    Ep[(quad * 4 + g) * 68 + j * 16 + r] = v;
                }
            }
            int grow0 = m0 + wm + i * 16;
            int cb = nloc + wn + c;
            if (om == 0) {
#pragma unroll
                for (int p = 0; p < 4; p++) {
                    float4 v = *(float4*)&Ep[(p * 4 + rr) * 68 + c];
                    half4 h;
                    h[0] = (_Float16)v.x; h[1] = (_Float16)v.y; h[2] = (_Float16)v.z; h[3] = (_Float16)v.w;
                    *(half4*)&((_Float16*)C)[(size_t)(grow0 + p * 4 + rr) * 512 + cb] = h;
                }
            } else if (om == 3) {
                float4 g4 = *(const float4*)(bng + cb);
                float4 b4 = *(const float4*)(bnb + cb);
                float4 m4 = *(const float4*)(bnm + cb);
                float4 v4 = *(const float4*)(bnv + cb);
                float s0 = g4.x * rsqrtf(v4.x + BN_EPS);
                float s1 = g4.y * rsqrtf(v4.y + BN_EPS);
                float s2 = g4.z * rsqrtf(v4.z + BN_EPS);
                float s3 = g4.w * rsqrtf(v4.w + BN_EPS);
#pragma unroll
                for (int p = 0; p < 4; p++) {
                    int grow = grow0 + p * 4 + rr;
                    float4 v = *(float4*)&Ep[(p * 4 + rr) * 68 + c];
                    half4 xv = *(const half4*)(xres + (size_t)grow * 512 + cb);
                    half4 h;
                    h[0] = (_Float16)((v.x + (float)xv[0] - m4.x) * s0 + b4.x);
                    h[1] = (_Float16)((v.y + (float)xv[1] - m4.y) * s1 + b4.y);
                    h[2] = (_Float16)((v.z + (float)xv[2] - m4.z) * s2 + b4.z);
                    h[3] = (_Float16)((v.w + (float)xv[3] - m4.w) * s3 + b4.w);
                    *(half4*)&((_Float16*)C)[(size_t)grow * 512 + cb] = h;
                }
            } else {            // om == 2: fp32 row-major width N
                if (cb < N) {
#pragma unroll
                    for (int p = 0; p < 4; p++) {
                        float4 v = *(float4*)&Ep[(p * 4 + rr) * 68 + c];
                        *(float4*)&((float*)C)[(size_t)(grow0 + p * 4 + rr) * N + cb] = v;
                    }
                }
            }
        }
    }
}

// ---------------- fused flash attention (fp16 in/out, fp32 softmax) ----------------
__global__ __launch_bounds__(256) void k_attn(const _Float16* __restrict__ Q, const _Float16* __restrict__ Kb,
                                              const _Float16* __restrict__ Vt, _Float16* __restrict__ O,
                                              int Sk, int causal) {
    __shared__ _Float16 Plds[4][16][72];
    int qt = blockIdx.x, h = blockIdx.y, b = blockIdx.z;
    int tid = threadIdx.x;
    int w = tid >> 6, lane = tid & 63, quad = lane >> 4, r = lane & 15;
    int qbase = qt * 64 + w * 16;

    floatx4 zf = {0.f, 0.f, 0.f, 0.f};
    half8 aq[2];
    const _Float16* qptr = Q + (size_t)(b * NS + qbase + r) * ND + h * NDK;
    aq[0] = *(const half8*)(qptr + quad * 8);
    aq[1] = *(const half8*)(qptr + 32 + quad * 8);

    floatx4 Of[4];
    for (int j = 0; j < 4; j++) Of[j] = zf;
    float mrow[4], lrow[4];
    for (int g = 0; g < 4; g++) { mrow[g] = -1e30f; lrow[g] = 0.0f; }

    int ntiles = causal ? (qt + 1) : (Sk >> 6);

    for (int kt = 0; kt < ntiles; kt++) {
        floatx4 sc[4];
        for (int j = 0; j < 4; j++) sc[j] = zf;
        for (int t = 0; t < 2; t++) {
            for (int j = 0; j < 4; j++) {
                const _Float16* kptr = Kb + (size_t)(b * Sk + kt * 64 + j * 16 + r) * ND + h * NDK + t * 32 + quad * 8;
                half8 bk = *(const half8*)kptr;
                sc[j] = __builtin_amdgcn_mfma_f32_16x16x32_f16(aq[t], bk, sc[j], 0, 0, 0);
            }
        }
        float s[4][4], tmax[4];
        for (int g = 0; g < 4; g++) tmax[g] = -1e30f;
        for (int j = 0; j < 4; j++) {
            int key = kt * 64 + j * 16 + r;
            for (int g = 0; g < 4; g++) {
                float v = sc[j][g] * 0.125f;
                int qi = qbase + quad * 4 + g;
                if (causal && key >= qi) v = -1e30f;
                s[j][g] = v;
                tmax[g] = fmaxf(tmax[g], v);
            }
        }
        for (int off = 1; off < 16; off <<= 1)
            for (int g = 0; g < 4; g++)
                tmax[g] = fmaxf(tmax[g], __shfl_xor(tmax[g], off, 64));
        float alpha[4], psum[4];
        for (int g = 0; g < 4; g++) {
            float mnew = fmaxf(mrow[g], tmax[g]);
            alpha[g] = (mnew <= -1e29f) ? 1.0f : __expf(mrow[g] - mnew);
            mrow[g] = mnew;
            psum[g] = 0.0f;
        }
        for (int j = 0; j < 4; j++) {
            for (int g = 0; g < 4; g++) {
                float p = (s[j][g] <= -1e29f) ? 0.0f : __expf(s[j][g] - mrow[g]);
                psum[g] += p;
                Plds[w][quad * 4 + g][j * 16 + r] = (_Float16)p;
            }
        }
        for (int off = 1; off < 16; off <<= 1)
            for (int g = 0; g < 4; g++)
                psum[g] += __shfl_xor(psum[g], off, 64);
        for (int g = 0; g < 4; g++) lrow[g] = lrow[g] * alpha[g] + psum[g];
        for (int j = 0; j < 4; j++)
            for (int g = 0; g < 4; g++)
                Of[j][g] *= alpha[g];
        __syncthreads();
        for (int t = 0; t < 2; t++) {
            half8 ap = *(const half8*)&Plds[w][r][t * 32 + quad * 8];
            for (int j = 0; j < 4; j++) {
                const _Float16* vptr = Vt + (size_t)((b * NH + h) * NDK + j * 16 + r) * Sk + kt * 64 + t * 32 + quad * 8;
                half8 bv = *(const half8*)vptr;
                Of[j] = __builtin_amdgcn_mfma_f32_16x16x32_f16(ap, bv, Of[j], 0, 0, 0);
            }
        }
        __syncthreads();
    }
    for (int j = 0; j < 4; j++) {
        for (int g = 0; g < 4; g++) {
            int row = qbase + quad * 4 + g;
            float inv = (lrow[g] > 0.f) ? 1.0f / lrow[g] : 0.0f;
            O[(size_t)(b * NS + row) * ND + h * NDK + j * 16 + r] = (_Float16)(Of[j][g] * inv);
        }
    }
}

extern "C" void kernel_launch(void* const* d_in, const int* in_sizes, int n_in,
                              void* d_out, int out_size, void* d_ws, size_t ws_size,
                              hipStream_t stream) {
    const int*   seq  = (const int*)d_in[0];
    const float* enc  = (const float*)d_in[1];
    const float* pos  = (const float*)d_in[2];
    const float* emb  = (const float*)d_in[3];
    const float* Wout = (const float*)d_in[4];
    const float* bout = (const float*)d_in[5];
    const float* W1   = (const float*)d_in[6];
    const float* b1   = (const float*)d_in[7];
    const float* W2   = (const float*)d_in[8];
    const float* b2   = (const float*)d_in[9];
    const float* Wq_bot = (const float*)d_in[10];
    const float* Wk_bot = (const float*)d_in[11];
    const float* Wv_bot = (const float*)d_in[12];
    const float* Wo_bot = (const float*)d_in[13];
    const float* bq_bot = (const float*)d_in[14];
    const float* bk_bot = (const float*)d_in[15];
    const float* bv_bot = (const float*)d_in[16];
    const float* bo_bot = (const float*)d_in[17];
    const float* Wq_mid = (const float*)d_in[18];
    const float* Wk_mid = (const float*)d_in[19];
    const float* Wv_mid = (const float*)d_in[20];
    const float* Wo_mid = (const float*)d_in[21];
    const float* bq_mid = (const float*)d_in[22];
    const float* bk_mid = (const float*)d_in[23];
    const float* bv_mid = (const float*)d_in[24];
    const float* bo_mid = (const float*)d_in[25];
    const float* gam[3] = {(const float*)d_in[26], (const float*)d_in[30], (const float*)d_in[34]};
    const float* bet[3] = {(const float*)d_in[27], (const float*)d_in[31], (const float*)d_in[35]};
    const float* mea[3] = {(const float*)d_in[28], (const float*)d_in[32], (const float*)d_in[36]};
    const float* vr [3] = {(const float*)d_in[29], (const float*)d_in[33], (const float*)d_in[37]};

    char* wp = (char*)d_ws;
    auto alloc = [&](size_t elems) -> _Float16* {
        _Float16* p = (_Float16*)wp;
        wp += ((elems * 2 + 255) / 256) * 256;
        return p;
    };
    const size_t DD = (size_t)ND * ND;
    _Float16* WqkvTb = alloc(NL * 3 * DD);      // [l][1536][512]: Wq^T,Wk^T,Wv^T
    _Float16* WoTb   = alloc(NL * DD);
    _Float16* WqTm   = alloc(NL * DD);
    _Float16* WkvTm  = alloc(NL * 2 * DD);      // [l][1024][512]: Wk^T,Wv^T
    _Float16* WoTm   = alloc(NL * DD);
    _Float16* W1T    = alloc(NL * DD);
    _Float16* W2T    = alloc(NL * DD);
    _Float16* WoutT  = alloc((size_t)NVP * ND);
    const size_t XSZ = (size_t)NB * NS * ND;
    _Float16* x   = alloc(XSZ);
    _Float16* qb  = alloc(XSZ);
    _Float16* kb  = alloc(XSZ);
    _Float16* vts = alloc(XSZ);                 // V^T self  [B,512,S]
    _Float16* ao  = alloc(XSZ);
    const size_t ESZ = (size_t)NB * NSE * ND;
    _Float16* ench  = alloc(ESZ);
    _Float16* kenc  = alloc(ESZ);
    _Float16* vtenc = alloc(ESZ);               // V^T cross [B,512,SE]

    // zero WoutT's padded tail rows (guard-free staging in the vocab GEMM)
    hipMemsetAsync(WoutT + (size_t)NV * ND, 0, (size_t)(NVP - NV) * ND * sizeof(_Float16), stream);

    dim3 tb(32, 8);
    const long long S1 = (long long)DD, S2 = (long long)(2 * DD), S3 = (long long)(3 * DD);
    k_transpose_w<<<dim3(16, 16, NL), tb, 0, stream>>>(Wq_bot, WqkvTb,          ND, ND, S3);
    k_transpose_w<<<dim3(16, 16, NL), tb, 0, stream>>>(Wk_bot, WqkvTb + DD,     ND, ND, S3);
    k_transpose_w<<<dim3(16, 16, NL), tb, 0, stream>>>(Wv_bot, WqkvTb + 2 * DD, ND, ND, S3);
    k_transpose_w<<<dim3(16, 16, NL), tb, 0, stream>>>(Wo_bot, WoTb,            ND, ND, S1);
    k_transpose_w<<<dim3(16, 16, NL), tb, 0, stream>>>(Wq_mid, WqTm,            ND, ND, S1);
    k_transpose_w<<<dim3(16, 16, NL), tb, 0, stream>>>(Wk_mid, WkvTm,           ND, ND, S2);
    k_transpose_w<<<dim3(16, 16, NL), tb, 0, stream>>>(Wv_mid, WkvTm + DD,      ND, ND, S2);
    k_transpose_w<<<dim3(16, 16, NL), tb, 0, stream>>>(Wo_mid, WoTm,            ND, ND, S1);
    k_transpose_w<<<dim3(16, 16, NL), tb, 0, stream>>>(W1,     W1T,             ND, ND, S1);
    k_transpose_w<<<dim3(16, 16, NL), tb, 0, stream>>>(W2,     W2T,             ND, ND, S1);
    k_transpose_w<<<dim3(NV / 32, 16, 1), tb, 0, stream>>>(Wout, WoutT, ND, NV, S1);
    k_cast<<<dim3((int)(ESZ / 8 / 256)), 256, 0, stream>>>(enc, ench);
    k_embed<<<dim3((int)(XSZ / 8 / 256)), 256, 0, stream>>>(seq, emb, pos, x);

    // N=512 GEMM, M=8192, BM=64/BK=128: grid (4,128) = 512 blocks
    auto gemm64 = [&](const _Float16* A, const _Float16* Bt, const float* b0, void* Cp,
                      int relu, int mode, const _Float16* xr, const float* g, const float* be,
                      const float* me, const float* ve) {
        k_gemm<64, 128><<<dim3(4, 128), 256, 0, stream>>>(A, Bt, b0, nullptr, nullptr,
            Cp, nullptr, nullptr, 8192, 512, 512, relu, mode, 0, xr, g, be, me, ve);
    };

    for (int l = 0; l < NL; l++) {
        size_t wofs = (size_t)l * DD;
        size_t bofs = (size_t)l * ND;
        // --- causal self-attention: fused QKV projection (N=1536) ---
        k_gemm<128, 64><<<dim3(12, 64), 256, 0, stream>>>(x, WqkvTb + (size_t)l * 3 * DD,
            bq_bot + bofs, bk_bot + bofs, bv_bot + bofs, qb, kb, vts,
            8192, 1536, 512, 0, 4, NS, nullptr, nullptr, nullptr, nullptr, nullptr);
        k_attn<<<dim3(NS / 64, NH, NB), 256, 0, stream>>>(qb, kb, vts, ao, NS, 1);
        gemm64(ao, WoTb + wofs, bo_bot + bofs, x, 0, 3, x,
               gam[0] + bofs, bet[0] + bofs, mea[0] + bofs, vr[0] + bofs);
        // --- cross-attention: Q proj + fused KV-encoder projection (N=1024) ---
        gemm64(x, WqTm + wofs, bq_mid + bofs, qb, 0, 0, nullptr, nullptr, nullptr, nullptr, nullptr);
        k_gemm<128, 64><<<dim3(8, 256), 256, 0, stream>>>(ench, WkvTm + (size_t)l * 2 * DD,
            bk_mid + bofs, bv_mid + bofs, nullptr, kenc, vtenc, nullptr,
            32768, 1024, 512, 0, 5, NSE, nullptr, nullptr, nullptr, nullptr, nullptr);
        k_attn<<<dim3(NS / 64, NH, NB), 256, 0, stream>>>(qb, kenc, vtenc, ao, NSE, 0);
        gemm64(ao, WoTm + wofs, bo_mid + bofs, x, 0, 3, x,
               gam[1] + bofs, bet[1] + bofs, mea[1] + bofs, vr[1] + bofs);
        // --- FFN ---
        gemm64(x, W1T + wofs, b1 + bofs, qb, 1, 0, nullptr, nullptr, nullptr, nullptr, nullptr);
        gemm64(qb, W2T + wofs, b2 + bofs, x, 0, 3, x,
               gam[2] + bofs, bet[2] + bofs, mea[2] + bofs, vr[2] + bofs);
    }
    // --- final vocab projection, fp32 straight to d_out ---
    k_gemm<128, 64><<<dim3(63, 64), 256, 0, stream>>>(x, WoutT, bout, nullptr, nullptr,
        d_out, nullptr, nullptr, 8192, NV, 512, 0, 2, 0, nullptr, nullptr, nullptr, nullptr, nullptr);
}

// Round 4
// 1764.514 us; speedup vs baseline: 2.7036x; 1.1176x over previous
//
#include <hip/hip_runtime.h>
#include <hip/hip_fp16.h>

typedef _Float16 half8 __attribute__((ext_vector_type(8)));
typedef _Float16 half4 __attribute__((ext_vector_type(4)));
typedef float floatx4 __attribute__((ext_vector_type(4)));

#define NB 32
#define NS 256
#define NSE 1024
#define ND 512
#define NV 8000
#define NVP 8064
#define NL 4
#define NH 8
#define NDK 64
#define BN_EPS 1e-3f

// ---- async global->LDS, 16B per lane (dest = wave-uniform base + lane*16) ----
typedef const __attribute__((address_space(1))) void* gas_ptr;
typedef __attribute__((address_space(3))) void* las_ptr;
__device__ __forceinline__ void gload16(const void* g, void* l) {
    __builtin_amdgcn_global_load_lds((gas_ptr)g, (las_ptr)l, 16, 0, 0);
}

// ---------------- fp32 -> fp16 cast (8 elems/thread) ----------------
__global__ __launch_bounds__(256) void k_cast(const float* __restrict__ in, _Float16* __restrict__ out) {
    size_t i = ((size_t)blockIdx.x * 256 + threadIdx.x) * 8;
    float4 a = *(const float4*)(in + i);
    float4 b = *(const float4*)(in + i + 4);
    half8 o;
    o[0] = (_Float16)a.x; o[1] = (_Float16)a.y; o[2] = (_Float16)a.z; o[3] = (_Float16)a.w;
    o[4] = (_Float16)b.x; o[5] = (_Float16)b.y; o[6] = (_Float16)b.z; o[7] = (_Float16)b.w;
    *(half8*)(out + i) = o;
}

// ---------------- embedding + positional (fp32 in, fp16 out) ----------------
__global__ __launch_bounds__(256) void k_embed(const int* __restrict__ seq,
                                               const float* __restrict__ emb,
                                               const float* __restrict__ pos,
                                               _Float16* __restrict__ x) {
    size_t i = ((size_t)blockIdx.x * 256 + threadIdx.x) * 8;
    int tok = (int)(i / ND);
    int d = (int)(i % ND);
    int s = tok % NS;
    int t = seq[tok];
    const float* ep = emb + (size_t)t * ND + d;
    const float* pp = pos + (size_t)s * ND + d;
    half8 o;
    for (int j = 0; j < 8; j++) o[j] = (_Float16)(ep[j] + pp[j]);
    *(half8*)(x + i) = o;
}

// ------------- weight transpose + cast: in fp32 [R][C] -> out fp16 [C][R] -------------
__global__ void k_transpose_w(const float* __restrict__ in, _Float16* __restrict__ out, int R, int C,
                              long long ostride) {
    __shared__ float tile[32][33];
    int b = blockIdx.z;
    int c0 = blockIdx.x * 32, r0 = blockIdx.y * 32;
    const float* pin = in + (size_t)b * R * C;
    _Float16* pout = out + (size_t)b * ostride;
    int tx = threadIdx.x, ty = threadIdx.y;                  // block (32,8)
    for (int j = 0; j < 32; j += 8)
        tile[ty + j][tx] = pin[(size_t)(r0 + ty + j) * C + c0 + tx];
    __syncthreads();
    for (int j = 0; j < 32; j += 8)
        pout[(size_t)(c0 + ty + j) * R + r0 + tx] = (_Float16)tile[tx][ty + j];
}

// ---------------- fp16 MFMA GEMM: C[M,N] = A[M,K] @ Bt[N,K]^T + bias ----------
// BM x 128 tile, 256 thr = 4 waves (2x2), BK=64.
// v4: 2-phase double-buffered K-loop (T3-min: prefetch next tile, counted
// vmcnt(LA), raw s_barrier) + T2 XOR-swizzled LDS (pre-swizzled global source,
// swizzled ds_read; rule #21). Epilogue stages in the free LDS buffer.
// mode: 0 = fp16 row-major (width 512) into C0
//       1 = fp16 per-batch transposed [b][col][Sb] into C0
//       2 = fp32 row-major width N (vocab, guard col<N) into C0
//       3 = fp16 row-major width 512, out = BN(xres + gemm) into C0
//       4 = fused QKV: seg(n0/512) 0->C0, 1->C1, 2->C2(mode1,Sb)
//       5 = fused KV : seg 0->C0, 1->C1(mode1,Sb)
template<int BM>
__global__ __launch_bounds__(256) void k_gemm(
    const _Float16* __restrict__ A, const _Float16* __restrict__ Bt,
    const float* __restrict__ bias0, const float* __restrict__ bias1, const float* __restrict__ bias2,
    void* __restrict__ C0, void* __restrict__ C1, void* __restrict__ C2,
    int M, int N, int K, int relu, int mode, int Sb,
    const _Float16* __restrict__ xres,
    const float* __restrict__ bng, const float* __restrict__ bnb,
    const float* __restrict__ bnm, const float* __restrict__ bnv) {
    constexpr int BN = 128;
    constexpr int BK = 64;
    constexpr int MI = BM / 32;                 // A-frags per wave
    constexpr int BUFH = (BM + BN) * BK;        // halfs per buffer
    constexpr int LA = (BM + BN) / 32;          // gload16 issues per lane per tile
    __shared__ __align__(16) _Float16 smem[2 * BUFH];

    int tid = threadIdx.x;
    int wid = tid >> 6, lane = tid & 63, quad = lane >> 4, r = lane & 15;

    // bijective XCD-aware swizzle
    int nwg = gridDim.x * gridDim.y;
    int orig = blockIdx.y * gridDim.x + blockIdx.x;
    int q8 = nwg >> 3, r8 = nwg & 7;
    int xcd = orig & 7, loc = orig >> 3;
    int swz = (xcd < r8 ? xcd * (q8 + 1) : r8 * (q8 + 1) + (xcd - r8) * q8) + loc;
    int m0 = (swz / gridDim.x) * BM;
    int n0 = (swz % gridDim.x) * BN;

    int wm = (wid >> 1) * (BM / 2);             // wave tile rows
    int wn = (wid & 1) * 64;

    floatx4 zf = {0.f, 0.f, 0.f, 0.f};
    floatx4 acc[MI][4];
    for (int i = 0; i < MI; i++) for (int j = 0; j < 4; j++) acc[i][j] = zf;

    // staging: 8 lanes/row (16B chunks), 8 rows/wave-issue, 32 rows/block-issue.
    // T2: lane loads global chunk (c ^ row&7) so LDS[row][c] = G[row][c ^ (row&7)]
    int srow = wid * 8 + (lane >> 3);
    int scol = (((lane & 7) ^ ((lane >> 3) & 7)) << 3);

    auto stage = [&](int k0, int buf) {
        _Float16* As = smem + buf * BUFH;
        _Float16* Bs = As + BM * BK;
        const _Float16* abase = A + (size_t)(m0 + srow) * K + k0 + scol;
        _Float16* asl = As + (wid * 8) * BK;
#pragma unroll
        for (int i = 0; i < BM / 32; i++)
            gload16(abase + (size_t)(i * 32) * K, asl + (i * 32) * BK);
        const _Float16* bbase = Bt + (size_t)(n0 + srow) * K + k0 + scol;
        _Float16* bsl = Bs + (wid * 8) * BK;
#pragma unroll
        for (int i = 0; i < 4; i++)
            gload16(bbase + (size_t)(i * 32) * K, bsl + (i * 32) * BK);
    };

    int NT = K / BK;
    int cur = 0;
    stage(0, 0);
    for (int t = 0; t < NT; t++) {
        if (t + 1 < NT) {
            stage((t + 1) * BK, cur ^ 1);
            asm volatile("s_waitcnt vmcnt(%0)" :: "n"(LA) : "memory");
        } else {
            asm volatile("s_waitcnt vmcnt(0)" ::: "memory");
        }
        __builtin_amdgcn_s_barrier();           // current tile ready in LDS
        const _Float16* As = smem + cur * BUFH;
        const _Float16* Bs = As + BM * BK;
#pragma unroll
        for (int ks = 0; ks < BK; ks += 32) {
            half8 af[MI], bg[4];
#pragma unroll
            for (int i = 0; i < MI; i++)
                af[i] = *(const half8*)&As[(wm + i * 16 + r) * BK + ((((ks >> 3) + quad) ^ (r & 7)) << 3)];
#pragma unroll
            for (int j = 0; j < 4; j++)
                bg[j] = *(const half8*)&Bs[(wn + j * 16 + r) * BK + ((((ks >> 3) + quad) ^ (r & 7)) << 3)];
#pragma unroll
            for (int i = 0; i < MI; i++)
#pragma unroll
                for (int j = 0; j < 4; j++)
                    acc[i][j] = __builtin_amdgcn_mfma_f32_16x16x32_f16(af[i], bg[j], acc[i][j], 0, 0, 0);
        }
        if (t + 1 < NT) {
            __builtin_amdgcn_s_barrier();       // all reads of buf done before re-stage
            cur ^= 1;
        }
    }

    // ---- resolve output routing (per-block uniform: BN=128 divides 512) ----
    int seg = 0, nloc = n0, om = mode;
    const float* bias = bias0;
    char* C = (char*)C0;
    if (mode == 4) {
        seg = n0 >> 9; nloc = n0 & 511;
        om = (seg == 2) ? 1 : 0;
        C = (char*)(seg == 0 ? C0 : (seg == 1 ? C1 : C2));
        bias = (seg == 0) ? bias0 : ((seg == 1) ? bias1 : bias2);
    } else if (mode == 5) {
        seg = n0 >> 9; nloc = n0 & 511;
        om = seg ? 1 : 0;
        C = (char*)(seg ? C1 : C0);
        bias = seg ? bias1 : bias0;
    }

    if (om == 1) {
        // transposed store: pack 4 consecutive-s accumulator elems into one half4
        for (int i = 0; i < MI; i++) {
            int grow = m0 + wm + i * 16 + quad * 4;
            int b = grow / Sb, s = grow - b * Sb;
            _Float16* outp = (_Float16*)C + (size_t)b * 512 * Sb + s;
#pragma unroll
            for (int j = 0; j < 4; j++) {
                int cb = nloc + wn + j * 16 + r;
                float bv = bias[cb];
                half4 h;
#pragma unroll
                for (int g = 0; g < 4; g++) h[g] = (_Float16)(acc[i][j][g] + bv);
                *(half4*)(outp + (size_t)cb * Sb) = h;
            }
        }
    } else {
        // per-wave fp32 staging tile [16][68] in the FREE double-buffer half
        // (no barrier needed: last compute only reads buf[cur]; regions per-wave disjoint)
        float* Ep = (float*)(void*)(smem + (cur ^ 1) * BUFH) + wid * (16 * 68);
        int rr = lane >> 4;
        int c = (lane & 15) * 4;
        for (int i = 0; i < MI; i++) {
#pragma unroll
            for (int j = 0; j < 4; j++) {
                int cb = nloc + wn + j * 16 + r;
                float bv = (om == 2) ? (cb < N ? bias[cb] : 0.0f) : bias[cb];
#pragma unroll
                for (int g = 0; g < 4; g++) {
                    float v = acc[i][j][g] + bv;
                    if (relu) v = fmaxf(v, 0.0f);
                    Ep[(quad * 4 + g) * 68 + j * 16 + r] = v;
                }
            }
            int grow0 = m0 + wm + i * 16;
            int cb = nloc + wn + c;
            if (om == 0) {
#pragma unroll
                for (int p = 0; p < 4; p++) {
                    float4 v = *(float4*)&Ep[(p * 4 + rr) * 68 + c];
                    half4 h;
                    h[0] = (_Float16)v.x; h[1] = (_Float16)v.y; h[2] = (_Float16)v.z; h[3] = (_Float16)v.w;
                    *(half4*)&((_Float16*)C)[(size_t)(grow0 + p * 4 + rr) * 512 + cb] = h;
                }
            } else if (om == 3) {
                float4 g4 = *(const float4*)(bng + cb);
                float4 b4 = *(const float4*)(bnb + cb);
                float4 m4 = *(const float4*)(bnm + cb);
                float4 v4 = *(const float4*)(bnv + cb);
                float s0 = g4.x * rsqrtf(v4.x + BN_EPS);
                float s1 = g4.y * rsqrtf(v4.y + BN_EPS);
                float s2 = g4.z * rsqrtf(v4.z + BN_EPS);
                float s3 = g4.w * rsqrtf(v4.w + BN_EPS);
#pragma unroll
                for (int p = 0; p < 4; p++) {
                    int grow = grow0 + p * 4 + rr;
                    float4 v = *(float4*)&Ep[(p * 4 + rr) * 68 + c];
                    half4 xv = *(const half4*)(xres + (size_t)grow * 512 + cb);
                    half4 h;
                    h[0] = (_Float16)((v.x + (float)xv[0] - m4.x) * s0 + b4.x);
                    h[1] = (_Float16)((v.y + (float)xv[1] - m4.y) * s1 + b4.y);
                    h[2] = (_Float16)((v.z + (float)xv[2] - m4.z) * s2 + b4.z);
                    h[3] = (_Float16)((v.w + (float)xv[3] - m4.w) * s3 + b4.w);
                    *(half4*)&((_Float16*)C)[(size_t)grow * 512 + cb] = h;
                }
            } else {            // om == 2: fp32 row-major width N
                if (cb < N) {
#pragma unroll
                    for (int p = 0; p < 4; p++) {
                        float4 v = *(float4*)&Ep[(p * 4 + rr) * 68 + c];
                        *(float4*)&((float*)C)[(size_t)(grow0 + p * 4 + rr) * N + cb] = v;
                    }
                }
            }
        }
    }
}

// ---------------- fused flash attention (fp16 in/out, fp32 softmax) ----------------
__global__ __launch_bounds__(256) void k_attn(const _Float16* __restrict__ Q, const _Float16* __restrict__ Kb,
                                              const _Float16* __restrict__ Vt, _Float16* __restrict__ O,
                                              int Sk, int causal) {
    __shared__ _Float16 Plds[4][16][72];
    int qt = blockIdx.x, h = blockIdx.y, b = blockIdx.z;
    int tid = threadIdx.x;
    int w = tid >> 6, lane = tid & 63, quad = lane >> 4, r = lane & 15;
    int qbase = qt * 64 + w * 16;

    floatx4 zf = {0.f, 0.f, 0.f, 0.f};
    half8 aq[2];
    const _Float16* qptr = Q + (size_t)(b * NS + qbase + r) * ND + h * NDK;
    aq[0] = *(const half8*)(qptr + quad * 8);
    aq[1] = *(const half8*)(qptr + 32 + quad * 8);

    floatx4 Of[4];
    for (int j = 0; j < 4; j++) Of[j] = zf;
    float mrow[4], lrow[4];
    for (int g = 0; g < 4; g++) { mrow[g] = -1e30f; lrow[g] = 0.0f; }

    int ntiles = causal ? (qt + 1) : (Sk >> 6);

    for (int kt = 0; kt < ntiles; kt++) {
        floatx4 sc[4];
        for (int j = 0; j < 4; j++) sc[j] = zf;
        for (int t = 0; t < 2; t++) {
            for (int j = 0; j < 4; j++) {
                const _Float16* kptr = Kb + (size_t)(b * Sk + kt * 64 + j * 16 + r) * ND + h * NDK + t * 32 + quad * 8;
                half8 bk = *(const half8*)kptr;
                sc[j] = __builtin_amdgcn_mfma_f32_16x16x32_f16(aq[t], bk, sc[j], 0, 0, 0);
            }
        }
        float s[4][4], tmax[4];
        for (int g = 0; g < 4; g++) tmax[g] = -1e30f;
        for (int j = 0; j < 4; j++) {
            int key = kt * 64 + j * 16 + r;
            for (int g = 0; g < 4; g++) {
                float v = sc[j][g] * 0.125f;
                int qi = qbase + quad * 4 + g;
                if (causal && key >= qi) v = -1e30f;
                s[j][g] = v;
                tmax[g] = fmaxf(tmax[g], v);
            }
        }
        for (int off = 1; off < 16; off <<= 1)
            for (int g = 0; g < 4; g++)
                tmax[g] = fmaxf(tmax[g], __shfl_xor(tmax[g], off, 64));
        float alpha[4], psum[4];
        for (int g = 0; g < 4; g++) {
            float mnew = fmaxf(mrow[g], tmax[g]);
            alpha[g] = (mnew <= -1e29f) ? 1.0f : __expf(mrow[g] - mnew);
            mrow[g] = mnew;
            psum[g] = 0.0f;
        }
        for (int j = 0; j < 4; j++) {
            for (int g = 0; g < 4; g++) {
                float p = (s[j][g] <= -1e29f) ? 0.0f : __expf(s[j][g] - mrow[g]);
                psum[g] += p;
                Plds[w][quad * 4 + g][j * 16 + r] = (_Float16)p;
            }
        }
        for (int off = 1; off < 16; off <<= 1)
            for (int g = 0; g < 4; g++)
                psum[g] += __shfl_xor(psum[g], off, 64);
        for (int g = 0; g < 4; g++) lrow[g] = lrow[g] * alpha[g] + psum[g];
        for (int j = 0; j < 4; j++)
            for (int g = 0; g < 4; g++)
                Of[j][g] *= alpha[g];
        __syncthreads();
        for (int t = 0; t < 2; t++) {
            half8 ap = *(const half8*)&Plds[w][r][t * 32 + quad * 8];
            for (int j = 0; j < 4; j++) {
                const _Float16* vptr = Vt + (size_t)((b * NH + h) * NDK + j * 16 + r) * Sk + kt * 64 + t * 32 + quad * 8;
                half8 bv = *(const half8*)vptr;
                Of[j] = __builtin_amdgcn_mfma_f32_16x16x32_f16(ap, bv, Of[j], 0, 0, 0);
            }
        }
        __syncthreads();
    }
    for (int j = 0; j < 4; j++) {
        for (int g = 0; g < 4; g++) {
            int row = qbase + quad * 4 + g;
            float inv = (lrow[g] > 0.f) ? 1.0f / lrow[g] : 0.0f;
            O[(size_t)(b * NS + row) * ND + h * NDK + j * 16 + r] = (_Float16)(Of[j][g] * inv);
        }
    }
}

extern "C" void kernel_launch(void* const* d_in, const int* in_sizes, int n_in,
                              void* d_out, int out_size, void* d_ws, size_t ws_size,
                              hipStream_t stream) {
    const int*   seq  = (const int*)d_in[0];
    const float* enc  = (const float*)d_in[1];
    const float* pos  = (const float*)d_in[2];
    const float* emb  = (const float*)d_in[3];
    const float* Wout = (const float*)d_in[4];
    const float* bout = (const float*)d_in[5];
    const float* W1   = (const float*)d_in[6];
    const float* b1   = (const float*)d_in[7];
    const float* W2   = (const float*)d_in[8];
    const float* b2   = (const float*)d_in[9];
    const float* Wq_bot = (const float*)d_in[10];
    const float* Wk_bot = (const float*)d_in[11];
    const float* Wv_bot = (const float*)d_in[12];
    const float* Wo_bot = (const float*)d_in[13];
    const float* bq_bot = (const float*)d_in[14];
    const float* bk_bot = (const float*)d_in[15];
    const float* bv_bot = (const float*)d_in[16];
    const float* bo_bot = (const float*)d_in[17];
    const float* Wq_mid = (const float*)d_in[18];
    const float* Wk_mid = (const float*)d_in[19];
    const float* Wv_mid = (const float*)d_in[20];
    const float* Wo_mid = (const float*)d_in[21];
    const float* bq_mid = (const float*)d_in[22];
    const float* bk_mid = (const float*)d_in[23];
    const float* bv_mid = (const float*)d_in[24];
    const float* bo_mid = (const float*)d_in[25];
    const float* gam[3] = {(const float*)d_in[26], (const float*)d_in[30], (const float*)d_in[34]};
    const float* bet[3] = {(const float*)d_in[27], (const float*)d_in[31], (const float*)d_in[35]};
    const float* mea[3] = {(const float*)d_in[28], (const float*)d_in[32], (const float*)d_in[36]};
    const float* vr [3] = {(const float*)d_in[29], (const float*)d_in[33], (const float*)d_in[37]};

    char* wp = (char*)d_ws;
    auto alloc = [&](size_t elems) -> _Float16* {
        _Float16* p = (_Float16*)wp;
        wp += ((elems * 2 + 255) / 256) * 256;
        return p;
    };
    const size_t DD = (size_t)ND * ND;
    _Float16* WqkvTb = alloc(NL * 3 * DD);      // [l][1536][512]: Wq^T,Wk^T,Wv^T
    _Float16* WoTb   = alloc(NL * DD);
    _Float16* WqTm   = alloc(NL * DD);
    _Float16* WkvTm  = alloc(NL * 2 * DD);      // [l][1024][512]: Wk^T,Wv^T
    _Float16* WoTm   = alloc(NL * DD);
    _Float16* W1T    = alloc(NL * DD);
    _Float16* W2T    = alloc(NL * DD);
    _Float16* WoutT  = alloc((size_t)NVP * ND);
    const size_t XSZ = (size_t)NB * NS * ND;
    _Float16* x   = alloc(XSZ);
    _Float16* qb  = alloc(XSZ);
    _Float16* kb  = alloc(XSZ);
    _Float16* vts = alloc(XSZ);                 // V^T self  [B,512,S]
    _Float16* ao  = alloc(XSZ);
    const size_t ESZ = (size_t)NB * NSE * ND;
    _Float16* ench  = alloc(ESZ);
    _Float16* kenc  = alloc(ESZ);
    _Float16* vtenc = alloc(ESZ);               // V^T cross [B,512,SE]

    // zero WoutT's padded tail rows (guard-free staging in the vocab GEMM)
    hipMemsetAsync(WoutT + (size_t)NV * ND, 0, (size_t)(NVP - NV) * ND * sizeof(_Float16), stream);

    dim3 tb(32, 8);
    const long long S1 = (long long)DD, S2 = (long long)(2 * DD), S3 = (long long)(3 * DD);
    k_transpose_w<<<dim3(16, 16, NL), tb, 0, stream>>>(Wq_bot, WqkvTb,          ND, ND, S3);
    k_transpose_w<<<dim3(16, 16, NL), tb, 0, stream>>>(Wk_bot, WqkvTb + DD,     ND, ND, S3);
    k_transpose_w<<<dim3(16, 16, NL), tb, 0, stream>>>(Wv_bot, WqkvTb + 2 * DD, ND, ND, S3);
    k_transpose_w<<<dim3(16, 16, NL), tb, 0, stream>>>(Wo_bot, WoTb,            ND, ND, S1);
    k_transpose_w<<<dim3(16, 16, NL), tb, 0, stream>>>(Wq_mid, WqTm,            ND, ND, S1);
    k_transpose_w<<<dim3(16, 16, NL), tb, 0, stream>>>(Wk_mid, WkvTm,           ND, ND, S2);
    k_transpose_w<<<dim3(16, 16, NL), tb, 0, stream>>>(Wv_mid, WkvTm + DD,      ND, ND, S2);
    k_transpose_w<<<dim3(16, 16, NL), tb, 0, stream>>>(Wo_mid, WoTm,            ND, ND, S1);
    k_transpose_w<<<dim3(16, 16, NL), tb, 0, stream>>>(W1,     W1T,             ND, ND, S1);
    k_transpose_w<<<dim3(16, 16, NL), tb, 0, stream>>>(W2,     W2T,             ND, ND, S1);
    k_transpose_w<<<dim3(NV / 32, 16, 1), tb, 0, stream>>>(Wout, WoutT, ND, NV, S1);
    k_cast<<<dim3((int)(ESZ / 8 / 256)), 256, 0, stream>>>(enc, ench);
    k_embed<<<dim3((int)(XSZ / 8 / 256)), 256, 0, stream>>>(seq, emb, pos, x);

    // N=512 GEMM, M=8192, BM=64: grid (4,128) = 512 blocks
    auto gemm64 = [&](const _Float16* A, const _Float16* Bt, const float* b0, void* Cp,
                      int relu, int mode, const _Float16* xr, const float* g, const float* be,
                      const float* me, const float* ve) {
        k_gemm<64><<<dim3(4, 128), 256, 0, stream>>>(A, Bt, b0, nullptr, nullptr,
            Cp, nullptr, nullptr, 8192, 512, 512, relu, mode, 0, xr, g, be, me, ve);
    };

    for (int l = 0; l < NL; l++) {
        size_t wofs = (size_t)l * DD;
        size_t bofs = (size_t)l * ND;
        // --- causal self-attention: fused QKV projection (N=1536) ---
        k_gemm<128><<<dim3(12, 64), 256, 0, stream>>>(x, WqkvTb + (size_t)l * 3 * DD,
            bq_bot + bofs, bk_bot + bofs, bv_bot + bofs, qb, kb, vts,
            8192, 1536, 512, 0, 4, NS, nullptr, nullptr, nullptr, nullptr, nullptr);
        k_attn<<<dim3(NS / 64, NH, NB), 256, 0, stream>>>(qb, kb, vts, ao, NS, 1);
        gemm64(ao, WoTb + wofs, bo_bot + bofs, x, 0, 3, x,
               gam[0] + bofs, bet[0] + bofs, mea[0] + bofs, vr[0] + bofs);
        // --- cross-attention: Q proj + fused KV-encoder projection (N=1024) ---
        gemm64(x, WqTm + wofs, bq_mid + bofs, qb, 0, 0, nullptr, nullptr, nullptr, nullptr, nullptr);
        k_gemm<128><<<dim3(8, 256), 256, 0, stream>>>(ench, WkvTm + (size_t)l * 2 * DD,
            bk_mid + bofs, bv_mid + bofs, nullptr, kenc, vtenc, nullptr,
            32768, 1024, 512, 0, 5, NSE, nullptr, nullptr, nullptr, nullptr, nullptr);
        k_attn<<<dim3(NS / 64, NH, NB), 256, 0, stream>>>(qb, kenc, vtenc, ao, NSE, 0);
        gemm64(ao, WoTm + wofs, bo_mid + bofs, x, 0, 3, x,
               gam[1] + bofs, bet[1] + bofs, mea[1] + bofs, vr[1] + bofs);
        // --- FFN ---
        gemm64(x, W1T + wofs, b1 + bofs, qb, 1, 0, nullptr, nullptr, nullptr, nullptr, nullptr);
        gemm64(qb, W2T + wofs, b2 + bofs, x, 0, 3, x,
               gam[2] + bofs, bet[2] + bofs, mea[2] + bofs, vr[2] + bofs);
    }
    // --- final vocab projection, fp32 straight to d_out ---
    k_gemm<128><<<dim3(63, 64), 256, 0, stream>>>(x, WoutT, bout, nullptr, nullptr,
        d_out, nullptr, nullptr, 8192, NV, 512, 0, 2, 0, nullptr, nullptr, nullptr, nullptr, nullptr);
}